// Round 5
// baseline (1336.629 us; speedup 1.0000x reference)
//
#include <hip/hip_runtime.h>
#include <hip/hip_bf16.h>

// MultiTokenPrediction: main head logits + fused CE for main + 2 aux heads.
// B=1, S=2048, D=1024, V=50257, heads predict t+1 (main), t+2, t+3 (aux).

typedef __hip_bfloat16 bf16;
typedef __attribute__((ext_vector_type(8))) short bf16x8;
typedef __attribute__((ext_vector_type(4))) float f32x4;

typedef const __attribute__((address_space(1))) void* gptr_t;
typedef __attribute__((address_space(3))) void* lptr_t;

#define S_LEN   2048
#define DMODEL  1024
#define VOCAB   50257
#define VPAD2   51200   // 200*256 (8x8x25 block swizzle bijective)
#define NT256   200     // VPAD2/256

__device__ __forceinline__ void gload_lds16(const void* g, void* l) {
  __builtin_amdgcn_global_load_lds((gptr_t)g, (lptr_t)l, 16, 0, 0);
}

// ---------------- f32 -> bf16 conversion with row zero-padding ----------------
__global__ __launch_bounds__(256) void k_cvt(const float* __restrict__ src,
                                             bf16* __restrict__ dst,
                                             long rows_src, long rows_pad) {
  const long total4 = rows_pad << 8;
  for (long i = (long)blockIdx.x * 256 + threadIdx.x; i < total4;
       i += (long)gridDim.x * 256) {
    const long e = i << 2;
    const long row = e >> 10;
    alignas(8) bf16 o[4];
    if (row < rows_src) {
      const float4 v = *(const float4*)(src + e);
      o[0] = __float2bfloat16(v.x); o[1] = __float2bfloat16(v.y);
      o[2] = __float2bfloat16(v.z); o[3] = __float2bfloat16(v.w);
    } else {
      o[0] = o[1] = o[2] = o[3] = __float2bfloat16(0.f);
    }
    *(uint2*)(dst + e) = *(const uint2*)o;
  }
}

// ---------------- RMSNorm row kernel: f32 in, bf16 out ----------------
__global__ __launch_bounds__(256) void k_rms(const float* __restrict__ x,
                                             const float* __restrict__ w,
                                             bf16* __restrict__ xn) {
  const int row = blockIdx.x;
  const int t = threadIdx.x;
  const float4 v = ((const float4*)(x + (size_t)row * DMODEL))[t];
  float ss = v.x*v.x + v.y*v.y + v.z*v.z + v.w*v.w;
  #pragma unroll
  for (int d = 1; d < 64; d <<= 1) ss += __shfl_xor(ss, d, 64);
  __shared__ float red[4];
  if ((t & 63) == 0) red[t >> 6] = ss;
  __syncthreads();
  const float tot = red[0] + red[1] + red[2] + red[3];
  const float scale = rsqrtf(tot * (1.f / DMODEL) + 1e-5f);
  const float4 wv = ((const float4*)w)[t];
  alignas(8) bf16 o[4];
  o[0] = __float2bfloat16(v.x * scale * wv.x);
  o[1] = __float2bfloat16(v.y * scale * wv.y);
  o[2] = __float2bfloat16(v.z * scale * wv.z);
  o[3] = __float2bfloat16(v.w * scale * wv.w);
  *(uint2*)(xn + (size_t)row * DMODEL + t * 4) = *(const uint2*)o;
}

// ============ 256x256 bf16 MFMA GEMM, K-half pipeline, fused CE ============
// C[m][n] = sum_k A[m][k]*B[n][k]. grid(1600): bm=(id>>3)&7, bn=(id&7)+8*(id>>6)
// (8 bm-siblings share id%8 -> same XCD -> B L2-shared; FETCH 166MB verified R4).
// K split into 32 halves of 32 cols. SLOTS rotating 32KB LDS slots
// (A 16KB + B 16KB each). During half j: stage half j+SLOTS-1 into slot
// (j-1)%SLOTS (freed at end of j-1); end-of-j vmcnt drains half j+1
// (issued 2*(SLOTS-2) phases earlier). 2 phases per half, 16 MFMA each.
// Slot layout per array: 16 subtiles [16r][32c] (1KB), logical byte
// (r,c)=(r>>4)*1024+(r&15)*64+c*2, physical = logical^((logical>>9)&1)<<5
// (st_16x32). Swizzle both sides: read offset XORed, DMA source col
// pre-swizzled, DMA dest linear (rule #21; conflict-free verified R3).
template<int SLOTS, bool WRITE_OUT, bool DO_CE>
__global__ __launch_bounds__(512, 2)
void k_gemm256(const bf16* __restrict__ A, const bf16* __restrict__ B,
               float* __restrict__ C, long ldc, int Nvalid,
               const int* __restrict__ targets, int shift,
               float* __restrict__ pmax, float* __restrict__ psum,
               float* __restrict__ ptgt, int ntiles) {
  __shared__ char lds[SLOTS * 32768 + 9216];

  const int t = threadIdx.x;
  const int w = t >> 6, l = t & 63;
  const int g = l >> 4, q = l & 15;
  const int wr = w >> 2, wc = w & 3;
  const int id = blockIdx.x;
  const int bm = (id >> 3) & 7;
  const int bn = (id & 7) + ((id >> 6) << 3);

  f32x4 acc[8][4];
  #pragma unroll
  for (int i = 0; i < 8; ++i)
    #pragma unroll
    for (int j = 0; j < 4; ++j)
      #pragma unroll
      for (int r = 0; r < 4; ++r) acc[i][j][r] = 0.f;

  // staging source pointers (per-lane); half j at byte offset j*64 (immediate)
  const int srow = (l >> 2);
  const int scol = ((l & 3) * 8) ^ (((l >> 5) & 1) * 16);   // pre-swizzled col
  const char* gA0 = (const char*)(A + (size_t)(bm * 256 + w * 32 + srow) * DMODEL + scol);
  const char* gA1 = gA0 + (size_t)16 * DMODEL * 2;
  const char* gB0 = (const char*)(B + (size_t)(bn * 256 + w * 32 + srow) * DMODEL + scol);
  const char* gB1 = gB0 + (size_t)16 * DMODEL * 2;

  // frag-read bases (st_16x32-swizzled lane offset)
  const int laneoff = (q * 64 + g * 16) ^ (((q >> 3) & 1) << 5);
  const char* rdA = lds + wr * 8192 + laneoff;
  const char* rdB = lds + 16384 + wc * 4096 + laneoff;

  auto lda = [&](int s, int mi) {
    return *(const bf16x8*)(rdA + s * 32768 + mi * 1024);
  };
  auto ldb = [&](int s, int ni) {
    return *(const bf16x8*)(rdB + s * 32768 + ni * 1024);
  };
  auto stageA = [&](int s, int koff) {
    char* lb = lds + s * 32768 + w * 2048;
    gload_lds16(gA0 + koff, lb);
    gload_lds16(gA1 + koff, lb + 1024);
  };
  auto stageB = [&](int s, int koff) {
    char* lb = lds + s * 32768 + 16384 + w * 2048;
    gload_lds16(gB0 + koff, lb);
    gload_lds16(gB1 + koff, lb + 1024);
  };

  // ---- prologue: stage halves 0..SLOTS-2; drain half 0 ----
  #pragma unroll
  for (int p = 0; p < SLOTS - 1; ++p) { stageA(p, p * 64); stageB(p, p * 64); }
  if constexpr (SLOTS == 4) asm volatile("s_waitcnt vmcnt(8)" ::: "memory");
  else if constexpr (SLOTS == 3) asm volatile("s_waitcnt vmcnt(4)" ::: "memory");
  else asm volatile("s_waitcnt vmcnt(0)" ::: "memory");
  __builtin_amdgcn_s_barrier();

  // ---- main loop: 32 K-halves, fully unrolled (all indices fold) ----
  #pragma unroll
  for (int j = 0; j < 32; ++j) {
    const int s = j % SLOTS;
    const int sp = (j + SLOTS - 1) % SLOTS;
    const int koff = (j + SLOTS - 1) * 64;
    const bool do_stage = (j + SLOTS - 1) < 32;
    bf16x8 a[4], b[4];

    // ---- P0: mi 0-3 ----
    #pragma unroll
    for (int mi = 0; mi < 4; ++mi) a[mi] = lda(s, mi);
    #pragma unroll
    for (int ni = 0; ni < 4; ++ni) b[ni] = ldb(s, ni);
    if (do_stage) stageA(sp, koff);
    __builtin_amdgcn_s_barrier();
    __builtin_amdgcn_s_setprio(1);
    #pragma unroll
    for (int mi = 0; mi < 4; ++mi)
      #pragma unroll
      for (int ni = 0; ni < 4; ++ni)
        acc[mi][ni] = __builtin_amdgcn_mfma_f32_16x16x32_bf16(a[mi], b[ni], acc[mi][ni], 0, 0, 0);
    __builtin_amdgcn_s_setprio(0);
    __builtin_amdgcn_s_barrier();

    // ---- P1: mi 4-7 ----
    #pragma unroll
    for (int mi = 0; mi < 4; ++mi) a[mi] = lda(s, 4 + mi);
    if (do_stage) stageB(sp, koff);
    __builtin_amdgcn_s_barrier();
    __builtin_amdgcn_s_setprio(1);
    #pragma unroll
    for (int mi = 0; mi < 4; ++mi)
      #pragma unroll
      for (int ni = 0; ni < 4; ++ni)
        acc[4 + mi][ni] = __builtin_amdgcn_mfma_f32_16x16x32_bf16(a[mi], b[ni], acc[4 + mi][ni], 0, 0, 0);
    __builtin_amdgcn_s_setprio(0);

    // end-of-half wait: drain half j+1; leave later halves in flight
    if (j < 31) {
      const int staged_hi = (j + SLOTS - 1 < 32) ? (j + SLOTS - 1) : 31;
      const int nrem = 4 * (staged_hi - (j + 1));
      if (nrem >= 8)      asm volatile("s_waitcnt vmcnt(8)" ::: "memory");
      else if (nrem == 4) asm volatile("s_waitcnt vmcnt(4)" ::: "memory");
      else                asm volatile("s_waitcnt vmcnt(0)" ::: "memory");
    }
    __builtin_amdgcn_s_barrier();
  }

  // ---------------- epilogue ----------------
  if constexpr (WRITE_OUT) {
    #pragma unroll
    for (int mi = 0; mi < 8; ++mi) {
      #pragma unroll
      for (int r = 0; r < 4; ++r) {
        const long row = bm * 256 + wr * 128 + mi * 16 + g * 4 + r;
        #pragma unroll
        for (int ni = 0; ni < 4; ++ni) {
          const int col = bn * 256 + wc * 64 + ni * 16 + q;
          if (col < Nvalid) C[row * ldc + col] = acc[mi][ni][r];
        }
      }
    }
  }

  if constexpr (DO_CE) {
    float* lds_m = (float*)(lds + SLOTS * 32768);   // [256][4]
    float* lds_s = lds_m + 1024;                    // [256][4]
    int* lds_tgt = (int*)(lds_s + 1024);            // [256]
    if (t < 256) {
      const int rowg = bm * 256 + t;
      lds_tgt[t] = (rowg < S_LEN - shift) ? targets[rowg + shift] : -1;
    }
    __syncthreads();
    #pragma unroll
    for (int mi = 0; mi < 8; ++mi) {
      #pragma unroll
      for (int r = 0; r < 4; ++r) {
        const int rl = wr * 128 + mi * 16 + g * 4 + r;
        const int tgt = lds_tgt[rl];
        float v[4];
        #pragma unroll
        for (int ni = 0; ni < 4; ++ni) {
          const int n = bn * 256 + wc * 64 + ni * 16 + q;
          const float av = acc[mi][ni][r];
          if (n == tgt) ptgt[bm * 256 + rl] = av;
          v[ni] = (n < Nvalid) ? av : -1e30f;
        }
        float m = fmaxf(fmaxf(v[0], v[1]), fmaxf(v[2], v[3]));
        #pragma unroll
        for (int d = 1; d < 16; d <<= 1) m = fmaxf(m, __shfl_xor(m, d, 64));
        float s = 0.f;
        #pragma unroll
        for (int ni = 0; ni < 4; ++ni) s += __expf(v[ni] - m);
        #pragma unroll
        for (int d = 1; d < 16; d <<= 1) s += __shfl_xor(s, d, 64);
        if (q == 0) { lds_m[rl * 4 + wc] = m; lds_s[rl * 4 + wc] = s; }
      }
    }
    __syncthreads();
    if (t < 256) {
      float M = lds_m[t * 4 + 0], Ssum = lds_s[t * 4 + 0];
      #pragma unroll
      for (int c = 1; c < 4; ++c) {
        const float m2 = lds_m[t * 4 + c], s2 = lds_s[t * 4 + c];
        const float nM = fmaxf(M, m2);
        Ssum = Ssum * __expf(M - nM) + s2 * __expf(m2 - nM);
        M = nM;
      }
      const size_t idx = (size_t)(bm * 256 + t) * ntiles + bn;
      pmax[idx] = M;
      psum[idx] = Ssum;
    }
  }
}

// ---------------- 128x128 GEMM (small d->d projection) ----------------
__global__ __launch_bounds__(256, 2)
void k_gemm(const bf16* __restrict__ A, const bf16* __restrict__ B,
            float* __restrict__ C, long ldc, int Nvalid) {
  constexpr int K = DMODEL;
  __shared__ bf16 As[128 * 32];
  __shared__ bf16 Bs[128 * 32];

  const int t = threadIdx.x;
  const int bn = blockIdx.x, bm = blockIdx.y;
  const int w = t >> 6, l = t & 63, g = l >> 4, q = l & 15;
  const int wr = w >> 1, wc = w & 1;

  f32x4 acc[4][4];
  #pragma unroll
  for (int i = 0; i < 4; ++i)
    #pragma unroll
    for (int j = 0; j < 4; ++j)
      #pragma unroll
      for (int r = 0; r < 4; ++r) acc[i][j][r] = 0.f;

  char* lA0 = (char*)As + w * 1024;
  char* lA1 = (char*)As + 4096 + w * 1024;
  char* lB0 = (char*)Bs + w * 1024;
  char* lB1 = (char*)Bs + 4096 + w * 1024;
  const char* gA0 = (const char*)(A + (size_t)(bm * 128 + (t >> 2)) * K) + (t & 3) * 16;
  const char* gA1 = gA0 + (size_t)64 * K * 2;
  const char* gB0 = (const char*)(B + (size_t)(bn * 128 + (t >> 2)) * K) + (t & 3) * 16;
  const char* gB1 = gB0 + (size_t)64 * K * 2;

  for (int k0 = 0; k0 < K; k0 += 32) {
    const int kb = k0 * 2;
    gload_lds16(gA0 + kb, lA0);
    gload_lds16(gA1 + kb, lA1);
    gload_lds16(gB0 + kb, lB0);
    gload_lds16(gB1 + kb, lB1);
    __syncthreads();
    bf16x8 a[4], b[4];
    #pragma unroll
    for (int mi = 0; mi < 4; ++mi)
      a[mi] = *(const bf16x8*)&As[(wr * 64 + mi * 16 + q) * 32 + g * 8];
    #pragma unroll
    for (int ni = 0; ni < 4; ++ni)
      b[ni] = *(const bf16x8*)&Bs[(wc * 64 + ni * 16 + q) * 32 + g * 8];
    #pragma unroll
    for (int mi = 0; mi < 4; ++mi)
      #pragma unroll
      for (int ni = 0; ni < 4; ++ni)
        acc[mi][ni] = __builtin_amdgcn_mfma_f32_16x16x32_bf16(a[mi], b[ni], acc[mi][ni], 0, 0, 0);
    __syncthreads();
  }

  #pragma unroll
  for (int mi = 0; mi < 4; ++mi) {
    #pragma unroll
    for (int r = 0; r < 4; ++r) {
      const long row = bm * 128 + wr * 64 + mi * 16 + g * 4 + r;
      #pragma unroll
      for (int ni = 0; ni < 4; ++ni) {
        const int col = bn * 128 + wc * 64 + ni * 16 + q;
        if (col < Nvalid) C[row * ldc + col] = acc[mi][ni][r];
      }
    }
  }
}

// ---------------- combine per-row partials -> NLL ----------------
__global__ __launch_bounds__(64) void k_combine(const float* __restrict__ pmax,
                                                const float* __restrict__ psum,
                                                const float* __restrict__ ptgt,
                                                float* __restrict__ nll,
                                                int ntiles, int nv) {
  const int r = blockIdx.x;
  const int l = threadIdx.x;
  float M = -1e30f, Ssum = 0.f;
  for (int tl = l; tl < ntiles; tl += 64) {
    const float m = pmax[(size_t)r * ntiles + tl];
    const float s = psum[(size_t)r * ntiles + tl];
    const float nM = fmaxf(M, m);
    Ssum = Ssum * __expf(M - nM) + s * __expf(m - nM);
    M = nM;
  }
  #pragma unroll
  for (int d = 1; d < 64; d <<= 1) {
    const float m2 = __shfl_xor(M, d, 64);
    const float s2 = __shfl_xor(Ssum, d, 64);
    const float nM = fmaxf(M, m2);
    Ssum = Ssum * __expf(M - nM) + s2 * __expf(m2 - nM);
    M = nM;
  }
  if (l == 0) nll[r] = (r < nv) ? (M + logf(Ssum) - ptgt[r]) : 0.f;
}

// ---------------- final loss ----------------
__global__ __launch_bounds__(256) void k_loss(const float* __restrict__ nll,
                                              float* __restrict__ out) {
  __shared__ float sh[256];
  const int t = threadIdx.x;
  float sums[3];
  #pragma unroll
  for (int h = 0; h < 3; ++h) {
    const int nv = 2047 - h;
    float s = 0.f;
    for (int r = t; r < nv; r += 256) s += nll[h * 2048 + r];
    sh[t] = s; __syncthreads();
    for (int off = 128; off > 0; off >>= 1) {
      if (t < off) sh[t] += sh[t + off];
      __syncthreads();
    }
    sums[h] = sh[0]; __syncthreads();
  }
  if (t == 0)
    out[0] = sums[0] / 2047.f + 0.3f * 0.5f * (sums[1] / 2046.f + sums[2] / 2045.f);
}

extern "C" void kernel_launch(void* const* d_in, const int* in_sizes, int n_in,
                              void* d_out, int out_size, void* d_ws, size_t ws_size,
                              hipStream_t stream) {
  const float* hidden      = (const float*)d_in[0];
  const int*   targets     = (const int*)d_in[1];
  const float* emb_w       = (const float*)d_in[2];
  const float* main_norm_w = (const float*)d_in[3];
  const float* aux_proj_w  = (const float*)d_in[4];
  const float* aux_norm_w  = (const float*)d_in[5];
  const float* aux_out_w   = (const float*)d_in[6];
  float* out = (float*)d_out;

  char* ws = (char*)d_ws;
  bf16*  Wb    = (bf16*)(ws);                   // [VPAD2][1024] bf16
  bf16*  hb    = (bf16*)(ws + 104857600);       // hidden bf16
  bf16*  xn    = (bf16*)(ws + 109051904);       // normalized input bf16
  bf16*  projb = (bf16*)(ws + 113246208);       // aux proj weights bf16
  float* hbuf  = (float*)(ws + 117440512);      // aux pre-norm f32
  float* pmax  = (float*)(ws + 125829120);      // [2048][200]
  float* psum  = (float*)(ws + 127467520);      // [2048][200]
  float* ptgt  = (float*)(ws + 129105920);      // [2048]
  float* nll   = (float*)(ws + 129114112);      // [3][2048]

  // prep
  k_cvt<<<2048, 256, 0, stream>>>(hidden, hb, 2048, 2048);
  k_cvt<<<2048, 256, 0, stream>>>(aux_proj_w, projb, 2048, 2048);
  k_rms<<<2048, 256, 0, stream>>>(hidden, main_norm_w, xn);

  // ---- main head (SLOTS=4: 3 halves in flight, cover 4 phases) ----
  k_cvt<<<2048, 256, 0, stream>>>(emb_w, Wb, VOCAB, VPAD2);
  k_gemm256<4, true, true><<<1600, 512, 0, stream>>>(
      xn, Wb, out, VOCAB, VOCAB, targets, 1, pmax, psum, ptgt, NT256);
  k_combine<<<2048, 64, 0, stream>>>(pmax, psum, ptgt, nll, NT256, 2047);

  // ---- aux head 0 (SLOTS=3: cover 2 phases) ----
  k_cvt<<<2048, 256, 0, stream>>>(aux_out_w, Wb, VOCAB, VPAD2);
  k_gemm<<<dim3(8, 16), 256, 0, stream>>>(hb, projb, hbuf, DMODEL, DMODEL);
  k_rms<<<2048, 256, 0, stream>>>(hbuf, aux_norm_w, xn);
  k_gemm256<3, false, true><<<1600, 512, 0, stream>>>(
      xn, Wb, nullptr, 0, VOCAB, targets, 2, pmax, psum, ptgt, NT256);
  k_combine<<<2048, 64, 0, stream>>>(pmax, psum, ptgt, nll + 2048, NT256, 2046);

  // ---- aux head 1 (SLOTS=2: shallow control, drain-to-0 each half) ----
  k_cvt<<<2048, 256, 0, stream>>>(aux_out_w + (size_t)VOCAB * DMODEL, Wb, VOCAB, VPAD2);
  k_gemm<<<dim3(8, 16), 256, 0, stream>>>(
      hb, projb + (size_t)DMODEL * DMODEL, hbuf, DMODEL, DMODEL);
  k_rms<<<2048, 256, 0, stream>>>(hbuf, aux_norm_w + DMODEL, xn);
  k_gemm256<2, false, true><<<1600, 512, 0, stream>>>(
      xn, Wb, nullptr, 0, VOCAB, targets, 3, pmax, psum, ptgt, NT256);
  k_combine<<<2048, 64, 0, stream>>>(pmax, psum, ptgt, nll + 2 * 2048, NT256, 2045);

  k_loss<<<1, 256, 0, stream>>>(nll, out + (size_t)S_LEN * VOCAB);
}

// Round 6
// 1335.186 us; speedup vs baseline: 1.0011x; 1.0011x over previous
//
#include <hip/hip_runtime.h>
#include <hip/hip_bf16.h>

// MultiTokenPrediction: main head logits + fused CE for main + 2 aux heads.
// B=1, S=2048, D=1024, V=50257, heads predict t+1 (main), t+2, t+3 (aux).

typedef __hip_bfloat16 bf16;
typedef __attribute__((ext_vector_type(8))) short bf16x8;
typedef __attribute__((ext_vector_type(4))) float f32x4;

typedef const __attribute__((address_space(1))) void* gptr_t;
typedef __attribute__((address_space(3))) void* lptr_t;

#define S_LEN   2048
#define DMODEL  1024
#define VOCAB   50257
#define VPAD2   51200   // 200*256 (8x8x25 block swizzle bijective)
#define NT256   200     // VPAD2/256

__device__ __forceinline__ void gload_lds16(const void* g, void* l) {
  __builtin_amdgcn_global_load_lds((gptr_t)g, (lptr_t)l, 16, 0, 0);
}

// ---------------- f32 -> bf16 conversion with row zero-padding ----------------
__global__ __launch_bounds__(256) void k_cvt(const float* __restrict__ src,
                                             bf16* __restrict__ dst,
                                             long rows_src, long rows_pad) {
  const long total4 = rows_pad << 8;
  for (long i = (long)blockIdx.x * 256 + threadIdx.x; i < total4;
       i += (long)gridDim.x * 256) {
    const long e = i << 2;
    const long row = e >> 10;
    alignas(8) bf16 o[4];
    if (row < rows_src) {
      const float4 v = *(const float4*)(src + e);
      o[0] = __float2bfloat16(v.x); o[1] = __float2bfloat16(v.y);
      o[2] = __float2bfloat16(v.z); o[3] = __float2bfloat16(v.w);
    } else {
      o[0] = o[1] = o[2] = o[3] = __float2bfloat16(0.f);
    }
    *(uint2*)(dst + e) = *(const uint2*)o;
  }
}

// ---------------- RMSNorm row kernel: f32 in, bf16 out ----------------
__global__ __launch_bounds__(256) void k_rms(const float* __restrict__ x,
                                             const float* __restrict__ w,
                                             bf16* __restrict__ xn) {
  const int row = blockIdx.x;
  const int t = threadIdx.x;
  const float4 v = ((const float4*)(x + (size_t)row * DMODEL))[t];
  float ss = v.x*v.x + v.y*v.y + v.z*v.z + v.w*v.w;
  #pragma unroll
  for (int d = 1; d < 64; d <<= 1) ss += __shfl_xor(ss, d, 64);
  __shared__ float red[4];
  if ((t & 63) == 0) red[t >> 6] = ss;
  __syncthreads();
  const float tot = red[0] + red[1] + red[2] + red[3];
  const float scale = rsqrtf(tot * (1.f / DMODEL) + 1e-5f);
  const float4 wv = ((const float4*)w)[t];
  alignas(8) bf16 o[4];
  o[0] = __float2bfloat16(v.x * scale * wv.x);
  o[1] = __float2bfloat16(v.y * scale * wv.y);
  o[2] = __float2bfloat16(v.z * scale * wv.z);
  o[3] = __float2bfloat16(v.w * scale * wv.w);
  *(uint2*)(xn + (size_t)row * DMODEL + t * 4) = *(const uint2*)o;
}

// ============ 256x256 bf16 MFMA GEMM, 4-slot K-half pipeline, fused CE ============
// C[m][n] = sum_k A[m][k]*B[n][k]. grid(1600): bm=(id>>3)&7, bn=(id&7)+8*(id>>6)
// (8 bm-siblings share id%8 -> same XCD -> B L2-shared; FETCH verified R4).
// K split into 32 halves of 32 cols; 4 rotating 32KB LDS slots (A 16KB + B 16KB).
// During half j: stage half j+3 into slot (j+3)%4 (freed at end of j-1);
// end-of-half vmcnt drains half j+1 (2 halves stay in flight). 2 phases/half.
// Slot layout per array: 16 subtiles [16r][32c] (1KB), logical byte
// (r,c)=(r>>4)*1024+(r&15)*64+c*2, physical = logical^((logical>>9)&1)<<5
// (st_16x32). Swizzle both sides: read offset XORed, DMA source col
// pre-swizzled, DMA dest linear (rule #21; conflict-free verified R3).
// DO_CVT: post-epilogue tail converts 32 rows/block of the NEXT head's W
// (f32->bf16, zero-padded) -- hides the next cvt under this GEMM.
template<bool WRITE_OUT, bool DO_CVT>
__global__ __launch_bounds__(512, 2)
void k_gemm256(const bf16* __restrict__ A, const bf16* __restrict__ B,
               float* __restrict__ C, long ldc, int Nvalid,
               const int* __restrict__ targets, int shift,
               float* __restrict__ pmax, float* __restrict__ psum,
               float* __restrict__ ptgt, int ntiles,
               const float* __restrict__ nextW, bf16* __restrict__ nextWb) {
  constexpr int SLOTS = 4;
  __shared__ char lds[SLOTS * 32768 + 9216];

  const int t = threadIdx.x;
  const int w = t >> 6, l = t & 63;
  const int g = l >> 4, q = l & 15;
  const int wr = w >> 2, wc = w & 3;
  const int id = blockIdx.x;
  const int bm = (id >> 3) & 7;
  const int bn = (id & 7) + ((id >> 6) << 3);

  f32x4 acc[8][4];
  #pragma unroll
  for (int i = 0; i < 8; ++i)
    #pragma unroll
    for (int j = 0; j < 4; ++j)
      #pragma unroll
      for (int r = 0; r < 4; ++r) acc[i][j][r] = 0.f;

  // staging source pointers (per-lane); half j at byte offset j*64 (immediate)
  const int srow = (l >> 2);
  const int scol = ((l & 3) * 8) ^ (((l >> 5) & 1) * 16);   // pre-swizzled col
  const char* gA0 = (const char*)(A + (size_t)(bm * 256 + w * 32 + srow) * DMODEL + scol);
  const char* gA1 = gA0 + (size_t)16 * DMODEL * 2;
  const char* gB0 = (const char*)(B + (size_t)(bn * 256 + w * 32 + srow) * DMODEL + scol);
  const char* gB1 = gB0 + (size_t)16 * DMODEL * 2;

  // frag-read bases (st_16x32-swizzled lane offset)
  const int laneoff = (q * 64 + g * 16) ^ (((q >> 3) & 1) << 5);
  const char* rdA = lds + wr * 8192 + laneoff;
  const char* rdB = lds + 16384 + wc * 4096 + laneoff;

  auto lda = [&](int s, int mi) {
    return *(const bf16x8*)(rdA + s * 32768 + mi * 1024);
  };
  auto ldb = [&](int s, int ni) {
    return *(const bf16x8*)(rdB + s * 32768 + ni * 1024);
  };
  auto stageA = [&](int s, int koff) {
    char* lb = lds + s * 32768 + w * 2048;
    gload_lds16(gA0 + koff, lb);
    gload_lds16(gA1 + koff, lb + 1024);
  };
  auto stageB = [&](int s, int koff) {
    char* lb = lds + s * 32768 + 16384 + w * 2048;
    gload_lds16(gB0 + koff, lb);
    gload_lds16(gB1 + koff, lb + 1024);
  };

  // ---- prologue: stage halves 0..2; drain half 0 ----
  #pragma unroll
  for (int p = 0; p < SLOTS - 1; ++p) { stageA(p, p * 64); stageB(p, p * 64); }
  asm volatile("s_waitcnt vmcnt(8)" ::: "memory");
  __builtin_amdgcn_s_barrier();

  // ---- main loop: 32 K-halves, fully unrolled (all indices fold) ----
  #pragma unroll
  for (int j = 0; j < 32; ++j) {
    const int s = j % SLOTS;
    const int sp = (j + SLOTS - 1) % SLOTS;
    const int koff = (j + SLOTS - 1) * 64;
    const bool do_stage = (j + SLOTS - 1) < 32;
    bf16x8 a[4], b[4];

    // ---- P0: mi 0-3 ----
    #pragma unroll
    for (int mi = 0; mi < 4; ++mi) a[mi] = lda(s, mi);
    #pragma unroll
    for (int ni = 0; ni < 4; ++ni) b[ni] = ldb(s, ni);
    if (do_stage) stageA(sp, koff);
    __builtin_amdgcn_s_barrier();
    __builtin_amdgcn_s_setprio(1);
    #pragma unroll
    for (int mi = 0; mi < 4; ++mi)
      #pragma unroll
      for (int ni = 0; ni < 4; ++ni)
        acc[mi][ni] = __builtin_amdgcn_mfma_f32_16x16x32_bf16(a[mi], b[ni], acc[mi][ni], 0, 0, 0);
    __builtin_amdgcn_s_setprio(0);
    __builtin_amdgcn_s_barrier();

    // ---- P1: mi 4-7 ----
    #pragma unroll
    for (int mi = 0; mi < 4; ++mi) a[mi] = lda(s, 4 + mi);
    if (do_stage) stageB(sp, koff);
    __builtin_amdgcn_s_barrier();
    __builtin_amdgcn_s_setprio(1);
    #pragma unroll
    for (int mi = 0; mi < 4; ++mi)
      #pragma unroll
      for (int ni = 0; ni < 4; ++ni)
        acc[4 + mi][ni] = __builtin_amdgcn_mfma_f32_16x16x32_bf16(a[mi], b[ni], acc[4 + mi][ni], 0, 0, 0);
    __builtin_amdgcn_s_setprio(0);

    // end-of-half wait: drain half j+1; leave later halves in flight
    if (j < 31) {
      const int staged_hi = (j + SLOTS - 1 < 32) ? (j + SLOTS - 1) : 31;
      const int nrem = 4 * (staged_hi - (j + 1));
      if (nrem >= 8)      asm volatile("s_waitcnt vmcnt(8)" ::: "memory");
      else if (nrem == 4) asm volatile("s_waitcnt vmcnt(4)" ::: "memory");
      else                asm volatile("s_waitcnt vmcnt(0)" ::: "memory");
    }
    __builtin_amdgcn_s_barrier();
  }

  // ---------------- epilogue: C write ----------------
  if constexpr (WRITE_OUT) {
    #pragma unroll
    for (int mi = 0; mi < 8; ++mi) {
      #pragma unroll
      for (int r = 0; r < 4; ++r) {
        const long row = bm * 256 + wr * 128 + mi * 16 + g * 4 + r;
        #pragma unroll
        for (int ni = 0; ni < 4; ++ni) {
          const int col = bn * 256 + wc * 64 + ni * 16 + q;
          if (col < Nvalid) C[row * ldc + col] = acc[mi][ni][r];
        }
      }
    }
  }

  // ---------------- fused CE partials ----------------
  {
    float* lds_m = (float*)(lds + SLOTS * 32768);   // [256][4]
    float* lds_s = lds_m + 1024;                    // [256][4]
    int* lds_tgt = (int*)(lds_s + 1024);            // [256]
    if (t < 256) {
      const int rowg = bm * 256 + t;
      lds_tgt[t] = (rowg < S_LEN - shift) ? targets[rowg + shift] : -1;
    }
    __syncthreads();
    #pragma unroll
    for (int mi = 0; mi < 8; ++mi) {
      #pragma unroll
      for (int r = 0; r < 4; ++r) {
        const int rl = wr * 128 + mi * 16 + g * 4 + r;
        const int tgt = lds_tgt[rl];
        float v[4];
        #pragma unroll
        for (int ni = 0; ni < 4; ++ni) {
          const int n = bn * 256 + wc * 64 + ni * 16 + q;
          const float av = acc[mi][ni][r];
          if (n == tgt) ptgt[bm * 256 + rl] = av;
          v[ni] = (n < Nvalid) ? av : -1e30f;
        }
        float m = fmaxf(fmaxf(v[0], v[1]), fmaxf(v[2], v[3]));
        #pragma unroll
        for (int d = 1; d < 16; d <<= 1) m = fmaxf(m, __shfl_xor(m, d, 64));
        float s = 0.f;
        #pragma unroll
        for (int ni = 0; ni < 4; ++ni) s += __expf(v[ni] - m);
        #pragma unroll
        for (int d = 1; d < 16; d <<= 1) s += __shfl_xor(s, d, 64);
        if (q == 0) { lds_m[rl * 4 + wc] = m; lds_s[rl * 4 + wc] = s; }
      }
    }
    __syncthreads();
    if (t < 256) {
      float M = lds_m[t * 4 + 0], Ssum = lds_s[t * 4 + 0];
      #pragma unroll
      for (int c = 1; c < 4; ++c) {
        const float m2 = lds_m[t * 4 + c], s2 = lds_s[t * 4 + c];
        const float nM = fmaxf(M, m2);
        Ssum = Ssum * __expf(M - nM) + s2 * __expf(m2 - nM);
        M = nM;
      }
      const size_t idx = (size_t)(bm * 256 + t) * ntiles + bn;
      pmax[idx] = M;
      psum[idx] = Ssum;
    }
  }

  // ---------------- tail: convert 32 rows of next head's W ----------------
  if constexpr (DO_CVT) {
    const int r = id * 32 + (t >> 4);          // 1600*32 = 51200 rows
    const int cb = (t & 15) * 4;               // f32 col base within 64-col stride
    bf16* drow = nextWb + (size_t)r * DMODEL;
    if (r < VOCAB) {
      const float* srcr = nextW + (size_t)r * DMODEL;
      #pragma unroll
      for (int i = 0; i < 16; ++i) {
        const float4 v = *(const float4*)(srcr + cb + i * 64);
        alignas(8) bf16 o[4];
        o[0] = __float2bfloat16(v.x); o[1] = __float2bfloat16(v.y);
        o[2] = __float2bfloat16(v.z); o[3] = __float2bfloat16(v.w);
        *(uint2*)(drow + cb + i * 64) = *(const uint2*)o;
      }
    } else {
      #pragma unroll
      for (int i = 0; i < 16; ++i)
        *(uint2*)(drow + cb + i * 64) = uint2{0u, 0u};
    }
  }
}

// ---------------- 128x128 GEMM (small d->d projection) ----------------
__global__ __launch_bounds__(256, 2)
void k_gemm(const bf16* __restrict__ A, const bf16* __restrict__ B,
            float* __restrict__ C, long ldc, int Nvalid) {
  constexpr int K = DMODEL;
  __shared__ bf16 As[128 * 32];
  __shared__ bf16 Bs[128 * 32];

  const int t = threadIdx.x;
  const int bn = blockIdx.x, bm = blockIdx.y;
  const int w = t >> 6, l = t & 63, g = l >> 4, q = l & 15;
  const int wr = w >> 1, wc = w & 1;

  f32x4 acc[4][4];
  #pragma unroll
  for (int i = 0; i < 4; ++i)
    #pragma unroll
    for (int j = 0; j < 4; ++j)
      #pragma unroll
      for (int r = 0; r < 4; ++r) acc[i][j][r] = 0.f;

  char* lA0 = (char*)As + w * 1024;
  char* lA1 = (char*)As + 4096 + w * 1024;
  char* lB0 = (char*)Bs + w * 1024;
  char* lB1 = (char*)Bs + 4096 + w * 1024;
  const char* gA0 = (const char*)(A + (size_t)(bm * 128 + (t >> 2)) * K) + (t & 3) * 16;
  const char* gA1 = gA0 + (size_t)64 * K * 2;
  const char* gB0 = (const char*)(B + (size_t)(bn * 128 + (t >> 2)) * K) + (t & 3) * 16;
  const char* gB1 = gB0 + (size_t)64 * K * 2;

  for (int k0 = 0; k0 < K; k0 += 32) {
    const int kb = k0 * 2;
    gload_lds16(gA0 + kb, lA0);
    gload_lds16(gA1 + kb, lA1);
    gload_lds16(gB0 + kb, lB0);
    gload_lds16(gB1 + kb, lB1);
    __syncthreads();
    bf16x8 a[4], b[4];
    #pragma unroll
    for (int mi = 0; mi < 4; ++mi)
      a[mi] = *(const bf16x8*)&As[(wr * 64 + mi * 16 + q) * 32 + g * 8];
    #pragma unroll
    for (int ni = 0; ni < 4; ++ni)
      b[ni] = *(const bf16x8*)&Bs[(wc * 64 + ni * 16 + q) * 32 + g * 8];
    #pragma unroll
    for (int mi = 0; mi < 4; ++mi)
      #pragma unroll
      for (int ni = 0; ni < 4; ++ni)
        acc[mi][ni] = __builtin_amdgcn_mfma_f32_16x16x32_bf16(a[mi], b[ni], acc[mi][ni], 0, 0, 0);
    __syncthreads();
  }

  #pragma unroll
  for (int mi = 0; mi < 4; ++mi) {
    #pragma unroll
    for (int r = 0; r < 4; ++r) {
      const long row = bm * 128 + wr * 64 + mi * 16 + g * 4 + r;
      #pragma unroll
      for (int ni = 0; ni < 4; ++ni) {
        const int col = bn * 128 + wc * 64 + ni * 16 + q;
        if (col < Nvalid) C[row * ldc + col] = acc[mi][ni][r];
      }
    }
  }
}

// ---------------- combine per-row partials -> NLL ----------------
__global__ __launch_bounds__(64) void k_combine(const float* __restrict__ pmax,
                                                const float* __restrict__ psum,
                                                const float* __restrict__ ptgt,
                                                float* __restrict__ nll,
                                                int ntiles, int nv) {
  const int r = blockIdx.x;
  const int l = threadIdx.x;
  float M = -1e30f, Ssum = 0.f;
  for (int tl = l; tl < ntiles; tl += 64) {
    const float m = pmax[(size_t)r * ntiles + tl];
    const float s = psum[(size_t)r * ntiles + tl];
    const float nM = fmaxf(M, m);
    Ssum = Ssum * __expf(M - nM) + s * __expf(m - nM);
    M = nM;
  }
  #pragma unroll
  for (int d = 1; d < 64; d <<= 1) {
    const float m2 = __shfl_xor(M, d, 64);
    const float s2 = __shfl_xor(Ssum, d, 64);
    const float nM = fmaxf(M, m2);
    Ssum = Ssum * __expf(M - nM) + s2 * __expf(m2 - nM);
    M = nM;
  }
  if (l == 0) nll[r] = (r < nv) ? (M + logf(Ssum) - ptgt[r]) : 0.f;
}

// ---------------- final loss ----------------
__global__ __launch_bounds__(256) void k_loss(const float* __restrict__ nll,
                                              float* __restrict__ out) {
  __shared__ float sh[256];
  const int t = threadIdx.x;
  float sums[3];
  #pragma unroll
  for (int h = 0; h < 3; ++h) {
    const int nv = 2047 - h;
    float s = 0.f;
    for (int r = t; r < nv; r += 256) s += nll[h * 2048 + r];
    sh[t] = s; __syncthreads();
    for (int off = 128; off > 0; off >>= 1) {
      if (t < off) sh[t] += sh[t + off];
      __syncthreads();
    }
    sums[h] = sh[0]; __syncthreads();
  }
  if (t == 0)
    out[0] = sums[0] / 2047.f + 0.3f * 0.5f * (sums[1] / 2046.f + sums[2] / 2045.f);
}

extern "C" void kernel_launch(void* const* d_in, const int* in_sizes, int n_in,
                              void* d_out, int out_size, void* d_ws, size_t ws_size,
                              hipStream_t stream) {
  const float* hidden      = (const float*)d_in[0];
  const int*   targets     = (const int*)d_in[1];
  const float* emb_w       = (const float*)d_in[2];
  const float* main_norm_w = (const float*)d_in[3];
  const float* aux_proj_w  = (const float*)d_in[4];
  const float* aux_norm_w  = (const float*)d_in[5];
  const float* aux_out_w   = (const float*)d_in[6];
  float* out = (float*)d_out;

  char* ws = (char*)d_ws;
  const size_t WBYTES = (size_t)VPAD2 * DMODEL * 2;   // 104,857,600
  const bool big = ws_size >= 2 * WBYTES + 30000000;  // need ~234 MB for ping-pong

  bf16* WbA = (bf16*)(ws);
  bf16* WbB = big ? (bf16*)(ws + WBYTES) : WbA;       // fallback: single buffer
  char* rest = ws + (big ? 2 * WBYTES : WBYTES);
  bf16*  hb    = (bf16*)(rest);
  bf16*  xn    = (bf16*)(rest + 4194304);
  bf16*  projb = (bf16*)(rest + 8388608);
  float* hbuf  = (float*)(rest + 12582912);
  float* pmax  = (float*)(rest + 20971520);
  float* psum  = (float*)(rest + 22609920);
  float* ptgt  = (float*)(rest + 24248320);
  float* nll   = (float*)(rest + 24256512);

  // prep (small)
  k_cvt<<<2048, 256, 0, stream>>>(hidden, hb, 2048, 2048);
  k_cvt<<<2048, 256, 0, stream>>>(aux_proj_w, projb, 2048, 2048);
  k_rms<<<2048, 256, 0, stream>>>(hidden, main_norm_w, xn);
  // main W upfront (only exposed cvt in the big path)
  k_cvt<<<2048, 256, 0, stream>>>(emb_w, WbA, VOCAB, VPAD2);

  if (big) {
    // ---- main head: GEMM(WbA) + tail-cvt of aux0's W into WbB ----
    k_gemm256<true, true><<<1600, 512, 0, stream>>>(
        xn, WbA, out, VOCAB, VOCAB, targets, 1, pmax, psum, ptgt, NT256,
        aux_out_w, WbB);
    k_combine<<<2048, 64, 0, stream>>>(pmax, psum, ptgt, nll, NT256, 2047);

    // ---- aux head 0: GEMM(WbB) + tail-cvt of aux1's W into WbA ----
    k_gemm<<<dim3(8, 16), 256, 0, stream>>>(hb, projb, hbuf, DMODEL, DMODEL);
    k_rms<<<2048, 256, 0, stream>>>(hbuf, aux_norm_w, xn);
    k_gemm256<false, true><<<1600, 512, 0, stream>>>(
        xn, WbB, nullptr, 0, VOCAB, targets, 2, pmax, psum, ptgt, NT256,
        aux_out_w + (size_t)VOCAB * DMODEL, WbA);
    k_combine<<<2048, 64, 0, stream>>>(pmax, psum, ptgt, nll + 2048, NT256, 2046);

    // ---- aux head 1: GEMM(WbA), no tail ----
    k_gemm<<<dim3(8, 16), 256, 0, stream>>>(
        hb, projb + (size_t)DMODEL * DMODEL, hbuf, DMODEL, DMODEL);
    k_rms<<<2048, 256, 0, stream>>>(hbuf, aux_norm_w + DMODEL, xn);
    k_gemm256<false, false><<<1600, 512, 0, stream>>>(
        xn, WbA, nullptr, 0, VOCAB, targets, 3, pmax, psum, ptgt, NT256,
        nullptr, nullptr);
    k_combine<<<2048, 64, 0, stream>>>(pmax, psum, ptgt, nll + 2 * 2048, NT256, 2045);
  } else {
    // fallback: single W buffer, explicit cvt per head (R4/R5 flow)
    k_gemm256<true, false><<<1600, 512, 0, stream>>>(
        xn, WbA, out, VOCAB, VOCAB, targets, 1, pmax, psum, ptgt, NT256,
        nullptr, nullptr);
    k_combine<<<2048, 64, 0, stream>>>(pmax, psum, ptgt, nll, NT256, 2047);
    for (int i = 0; i < 2; ++i) {
      k_cvt<<<2048, 256, 0, stream>>>(aux_out_w + (size_t)i * VOCAB * DMODEL, WbA, VOCAB, VPAD2);
      k_gemm<<<dim3(8, 16), 256, 0, stream>>>(
          hb, projb + (size_t)i * DMODEL * DMODEL, hbuf, DMODEL, DMODEL);
      k_rms<<<2048, 256, 0, stream>>>(hbuf, aux_norm_w + (size_t)i * DMODEL, xn);
      k_gemm256<false, false><<<1600, 512, 0, stream>>>(
          xn, WbA, nullptr, 0, VOCAB, targets, i + 2, pmax, psum, ptgt, NT256,
          nullptr, nullptr);
      k_combine<<<2048, 64, 0, stream>>>(pmax, psum, ptgt, nll + (i + 1) * 2048, NT256, 2048 - (i + 2));
    }
  }

  k_loss<<<1, 256, 0, stream>>>(nll, out + (size_t)S_LEN * VOCAB);
}